// Round 14
// baseline (715.024 us; speedup 1.0000x reference)
//
#include <hip/hip_runtime.h>
#include <hip/hip_bf16.h>

typedef _Float16 f16;
typedef _Float16 f16x4 __attribute__((ext_vector_type(4)));
typedef _Float16 f16x8 __attribute__((ext_vector_type(8)));
typedef float f32x4 __attribute__((ext_vector_type(4)));

__device__ __forceinline__ void gload16(const void* g, void* l) {
    __builtin_amdgcn_global_load_lds(
        (const __attribute__((address_space(1))) void*)g,
        (__attribute__((address_space(3))) void*)l, 16, 0, 0);
}

#define FENCE asm volatile("" ::: "memory")
#define BARRIER do { FENCE; __builtin_amdgcn_s_barrier(); FENCE; } while (0)

// ===========================================================================
// Token-axis permutation pi (within every 64-col group): pi(j*16+c) = c*4+j.
// Applied to P cols, vT cols, PV-partial cols. PV's dot product over the
// token axis is invariant because P and vT are permuted identically.
// pi lets each lane store its 4 j-frag values as ONE 8B f16x4 (coalesced,
// no read-modify-write half-line amplification).
// ===========================================================================

// ===========================================================================
// 8-phase 256x256 BT-GEMM core (verified r8-r12).
// ===========================================================================
#define PHASE_MFMA(QI, QJ)                                                    \
    __builtin_amdgcn_s_setprio(1);                                            \
    _Pragma("unroll")                                                         \
    for (int ks = 0; ks < 2; ++ks)                                            \
      _Pragma("unroll")                                                       \
      for (int i = 0; i < 4; ++i)                                             \
        _Pragma("unroll")                                                     \
        for (int j = 0; j < 2; ++j)                                           \
          acc[(QI)*4 + i][(QJ)*2 + j] = __builtin_amdgcn_mfma_f32_16x16x32_f16( \
              a[i][ks], b[j][ks], acc[(QI)*4 + i][(QJ)*2 + j], 0, 0, 0);      \
    __builtin_amdgcn_s_setprio(0);

#define BT8_BODY(KBASE, NTILES)                                               \
    const int rr8 = lane >> 3;                                                \
    const int cs  = ((lane & 7) ^ rr8) << 3;                                  \
    const int ldsr = wid << 3;                                                \
    auto stageA = [&](int kt, int c, int h) {                                 \
        const size_t g0 = (size_t)(bm + (h << 7) + ldsr + rr8) * lda + (KBASE) + kt + cs; \
        gload16(A + g0,                      &sA[c][((h << 7) + ldsr) << 6]); \
        gload16(A + g0 + ((size_t)lda << 6), &sA[c][((h << 7) + 64 + ldsr) << 6]); \
    };                                                                        \
    auto stageB = [&](int kt, int c, int h) {                                 \
        const size_t g0 = (size_t)(bn + (h << 7) + ldsr + rr8) * ldb + (KBASE) + kt + cs; \
        gload16(B + g0,                      &sB[c][((h << 7) + ldsr) << 6]); \
        gload16(B + g0 + ((size_t)ldb << 6), &sB[c][((h << 7) + 64 + ldsr) << 6]); \
    };                                                                        \
    f32x4 acc[8][4] = {};                                                     \
    f16x8 a[4][2], b[2][2];                                                   \
    auto loadA = [&](int c, int qi) {                                         \
        _Pragma("unroll")                                                     \
        for (int i = 0; i < 4; ++i) {                                         \
            const int ra = wr * 128 + (qi * 4 + i) * 16 + (lane & 15);        \
            const int swz = (ra & 7) << 3;                                    \
            _Pragma("unroll")                                                 \
            for (int ks = 0; ks < 2; ++ks) {                                  \
                const int kk = ks * 32 + (lane >> 4) * 8;                     \
                a[i][ks] = *(const f16x8*)(&sA[c][(ra << 6) + (kk ^ swz)]);   \
            }                                                                 \
        }                                                                     \
    };                                                                        \
    auto loadB = [&](int c, int qj) {                                         \
        _Pragma("unroll")                                                     \
        for (int j = 0; j < 2; ++j) {                                         \
            const int rb = wc * 64 + (qj * 2 + j) * 16 + (lane & 15);         \
            const int swz = (rb & 7) << 3;                                    \
            _Pragma("unroll")                                                 \
            for (int ks = 0; ks < 2; ++ks) {                                  \
                const int kk = ks * 32 + (lane >> 4) * 8;                     \
                b[j][ks] = *(const f16x8*)(&sB[c][(rb << 6) + (kk ^ swz)]);   \
            }                                                                 \
        }                                                                     \
    };                                                                        \
    stageA(0, 0, 0); stageA(0, 0, 1); stageB(0, 0, 0); stageB(0, 0, 1);       \
    asm volatile("s_waitcnt vmcnt(0)" ::: "memory");                          \
    BARRIER;                                                                  \
    for (int g = 0; g < (NTILES); ++g) {                                      \
        const int c = g & 1, cn = c ^ 1;                                      \
        const int kn = (g + 1) << 6;                                          \
        const bool more = (g + 1) < (NTILES);                                 \
        loadA(c, 0); loadB(c, 0);                                             \
        if (more) { stageA(kn, cn, 0); stageA(kn, cn, 1); }                   \
        BARRIER; PHASE_MFMA(0, 0); BARRIER;                                   \
        loadB(c, 1);                                                          \
        if (more) { stageB(kn, cn, 0); stageB(kn, cn, 1); }                   \
        BARRIER; PHASE_MFMA(0, 1); BARRIER;                                   \
        loadA(c, 1); loadB(c, 0);                                             \
        BARRIER; PHASE_MFMA(1, 0); BARRIER;                                   \
        loadB(c, 1);                                                          \
        asm volatile("s_waitcnt vmcnt(0)" ::: "memory");                      \
        BARRIER; PHASE_MFMA(1, 1); BARRIER;                                   \
    }

// ===========================================================================
// Projection GEMM (verified): C = A B^T, f16 in, f16 out, ldc-interleaved.
// (q/k outputs are consumed row-wise by QK staging -> no pack here.)
// ===========================================================================
template<bool F16OUT>
__global__ __launch_bounds__(512) void gemm_bt8(
    const f16* __restrict__ A, const f16* __restrict__ B, void* __restrict__ Cv,
    int K, int lda, int ldb, int ldc, float scale, int nbn)
{
    __shared__ f16 sA[2][256 * 64];
    __shared__ f16 sB[2][256 * 64];
    const int tid = threadIdx.x, lane = tid & 63, wid = tid >> 6;
    const int wr = wid >> 2, wc = wid & 3;
    const int cpx = gridDim.x >> 3;
    const int wg = (blockIdx.x & 7) * cpx + (blockIdx.x >> 3);
    const int bm = (wg / nbn) << 8, bn = (wg % nbn) << 8;

    BT8_BODY(0, K >> 6)

#pragma unroll
    for (int i = 0; i < 8; ++i)
#pragma unroll
        for (int j = 0; j < 4; ++j)
#pragma unroll
            for (int r = 0; r < 4; ++r) {
                const int row = bm + wr * 128 + i * 16 + ((lane >> 4) << 2) + r;
                const int col = bn + wc * 64 + j * 16 + (lane & 15);
                if constexpr (F16OUT)
                    ((f16*)Cv)[(size_t)row * ldc + col] = (f16)(acc[i][j][r] * scale);
                else
                    ((float*)Cv)[(size_t)row * ldc + col] = acc[i][j][r] * scale;
            }
}

// ===========================================================================
// QK + tile-local softmax epilogue. P stored pi-PERMUTED, packed f16x4.
// Per 256-col tile t, per row: m_t, s_t stats; P = exp(S - m_t).
// ===========================================================================
__global__ __launch_bounds__(512) void gemm_qk(
    const f16* __restrict__ A, const f16* __restrict__ B,
    f16* __restrict__ P, float* __restrict__ mst, float* __restrict__ sst,
    int lda, int ldb)
{
    __shared__ f16 sA[2][256 * 64];
    __shared__ f16 sB[2][256 * 64];
    const int tid = threadIdx.x, lane = tid & 63, wid = tid >> 6;
    const int wr = wid >> 2, wc = wid & 3;
    const int cpx = gridDim.x >> 3;
    const int wg = (blockIdx.x & 7) * cpx + (blockIdx.x >> 3);
    const int bm = (wg >> 4) << 8, bn = (wg & 15) << 8;   // nbn = 16

    BT8_BODY(0, 16)

    // ---- tile-local softmax stats (reuse sA as f32 scratch) ----
    float* red = (float*)sA;
    const int lg = lane >> 4;
#pragma unroll
    for (int i = 0; i < 8; ++i)
#pragma unroll
        for (int r = 0; r < 4; ++r) {
            float v = fmaxf(fmaxf(acc[i][0][r], acc[i][1][r]),
                            fmaxf(acc[i][2][r], acc[i][3][r]));
#pragma unroll
            for (int msk = 1; msk <= 8; msk <<= 1) v = fmaxf(v, __shfl_xor(v, msk));
            if ((lane & 15) == 0) red[wr * 512 + (i * 16 + lg * 4 + r) * 4 + wc] = v;
        }
    BARRIER;
    float mloc[8][4];
#pragma unroll
    for (int i = 0; i < 8; ++i)
#pragma unroll
        for (int r = 0; r < 4; ++r) {
            const float4 q = *(const float4*)&red[wr * 512 + (i * 16 + lg * 4 + r) * 4];
            mloc[i][r] = fmaxf(fmaxf(q.x, q.y), fmaxf(q.z, q.w));
        }
    BARRIER;
#pragma unroll
    for (int i = 0; i < 8; ++i)
#pragma unroll
        for (int r = 0; r < 4; ++r) {
            float s = 0.f;
#pragma unroll
            for (int j = 0; j < 4; ++j) {
                const float e = __expf(acc[i][j][r] - mloc[i][r]);
                acc[i][j][r] = e; s += e;
            }
#pragma unroll
            for (int msk = 1; msk <= 8; msk <<= 1) s += __shfl_xor(s, msk);
            if ((lane & 15) == 0) red[wr * 512 + (i * 16 + lg * 4 + r) * 4 + wc] = s;
        }
    BARRIER;
    const int t4 = bn >> 8;
    if ((lane & 15) == 0) {
#pragma unroll
        for (int i = 0; i < 8; ++i)
#pragma unroll
            for (int r = 0; r < 4; ++r) {
                const int row128 = i * 16 + lg * 4 + r;
                const float4 q = *(const float4*)&red[wr * 512 + row128 * 4];
                const int grow = bm + wr * 128 + row128;
                mst[t4 * 4096 + grow] = mloc[i][r];
                sst[t4 * 4096 + grow] = (q.x + q.y) + (q.z + q.w);
            }
    }
    // ---- P store: pi-packed f16x4 per (i,r) -> 8B coalesced stores ----
#pragma unroll
    for (int i = 0; i < 8; ++i)
#pragma unroll
        for (int r = 0; r < 4; ++r) {
            const int grow = bm + wr * 128 + i * 16 + lg * 4 + r;
            f16x4 pk = { (f16)acc[i][0][r], (f16)acc[i][1][r],
                         (f16)acc[i][2][r], (f16)acc[i][3][r] };
            *(f16x4*)(P + (size_t)grow * 4096 + bn + wc * 64 + (lane & 15) * 4) = pk;
        }
}

// ===========================================================================
// scale_p: one block per row. m = max_t m_t, l = sum_t s_t e^{m_t-m};
// P[row][p] *= e^{m_{p>>8}-m} / (32 l), in place. (pi never crosses a
// 256-tile, so the per-position factor is unchanged by the permutation.)
// ===========================================================================
__global__ __launch_bounds__(256) void scale_p(
    f16* __restrict__ P, const float* __restrict__ mst, const float* __restrict__ sst)
{
    const int row = blockIdx.x;
    float m = -1e30f;
#pragma unroll
    for (int t = 0; t < 16; ++t) m = fmaxf(m, mst[t * 4096 + row]);
    float l = 0.f;
#pragma unroll
    for (int t = 0; t < 16; ++t) l += sst[t * 4096 + row] * __expf(mst[t * 4096 + row] - m);
    const float inv = 1.0f / (32.0f * l);
    const float f = __expf(mst[(threadIdx.x >> 4) * 4096 + row] - m) * inv;
    f16* p = P + (size_t)row * 4096 + threadIdx.x * 16;
    f16x8 va = *(f16x8*)p, vb = *(f16x8*)(p + 8);
#pragma unroll
    for (int u = 0; u < 8; ++u) {
        va[u] = (f16)((float)va[u] * f);
        vb[u] = (f16)((float)vb[u] * f);
    }
    *(f16x8*)p = va;
    *(f16x8*)(p + 8) = vb;
}

// ===========================================================================
// PV: bt8 core + split-K=4, plain stores. z=3 stores f32 direct (coalesced);
// z=0..2 store pi-packed f16x4 partials [z][4096][1024] (d-cols permuted).
// ===========================================================================
__global__ __launch_bounds__(512) void gemm_pv8(
    const f16* __restrict__ A, const f16* __restrict__ B, float* __restrict__ Cout,
    f16* __restrict__ Pp, int lda, int ldb)
{
    __shared__ f16 sA[2][256 * 64];
    __shared__ f16 sB[2][256 * 64];
    const int tid = threadIdx.x, lane = tid & 63, wid = tid >> 6;
    const int wr = wid >> 2, wc = wid & 3;
    const int cpx = gridDim.x >> 3;
    const int wg = (blockIdx.x & 7) * cpx + (blockIdx.x >> 3);
    const int bm = (wg >> 2) << 8, bn = (wg & 3) << 8;
    const int z = blockIdx.y;
    const int kbase = z << 10;

    BT8_BODY(kbase, 16)

    if (z == 3) {
#pragma unroll
        for (int i = 0; i < 8; ++i)
#pragma unroll
            for (int j = 0; j < 4; ++j)
#pragma unroll
                for (int r = 0; r < 4; ++r) {
                    const int row = bm + wr * 128 + i * 16 + ((lane >> 4) << 2) + r;
                    const int col = bn + wc * 64 + j * 16 + (lane & 15);
                    Cout[((size_t)row << 10) + col] = acc[i][j][r];
                }
    } else {
#pragma unroll
        for (int i = 0; i < 8; ++i)
#pragma unroll
            for (int r = 0; r < 4; ++r) {
                const int row = bm + wr * 128 + i * 16 + ((lane >> 4) << 2) + r;
                f16x4 pk = { (f16)acc[i][0][r], (f16)acc[i][1][r],
                             (f16)acc[i][2][r], (f16)acc[i][3][r] };
                *(f16x4*)(Pp + (size_t)z * 4194304 + ((size_t)row << 10)
                          + bn + wc * 64 + (lane & 15) * 4) = pk;
            }
    }
}

// ===========================================================================
// reduce_pv: out += p0+p1+p2, partials pi-permuted. Thread owns 8
// pi-consecutive entries = out cols {j*16+2g, j*16+2g+1 : j=0..3} of one
// 64-block. f16x8 partial reads and per-j float2 out accesses: coalesced.
// ===========================================================================
__global__ __launch_bounds__(256) void reduce_pv(
    float* __restrict__ Cout, const f16* __restrict__ Pp)
{
    const int i = blockIdx.x * 256 + threadIdx.x;   // 524288 threads
    const int r = i >> 7;
    const int c2 = i & 127;
    const int bb = (c2 >> 3) << 6;   // 64-block base
    const int g  = c2 & 7;
    const size_t pbase = ((size_t)r << 10) + bb + g * 8;
    const f16x8 p0 = *(const f16x8*)(Pp + pbase);
    const f16x8 p1 = *(const f16x8*)(Pp + pbase + 4194304);
    const f16x8 p2 = *(const f16x8*)(Pp + pbase + 8388608);
    float* o = Cout + ((size_t)r << 10) + bb;
#pragma unroll
    for (int j = 0; j < 4; ++j) {
        float2 v = *(float2*)(o + j * 16 + 2 * g);
        v.x += (float)p0[j]     + (float)p1[j]     + (float)p2[j];
        v.y += (float)p0[4 + j] + (float)p1[4 + j] + (float)p2[4 + j];
        *(float2*)(o + j * 16 + 2 * g) = v;
    }
}

// ===========================================================================
// 128x128 BT-GEMM, F16IN + PIPE (verified) — used for vT. PACK: pi-packed
// f16x4 stores (token-cols permuted to match P).
// ===========================================================================
template<bool F16IN, bool F16OUT, bool PIPE, bool PACK>
__global__ __launch_bounds__(256) void gemm_bt(
    const void* __restrict__ Av, const void* __restrict__ Bv, void* __restrict__ Cv,
    int K, int lda, int ldb, int ldc, float scale)
{
    constexpr int NB = PIPE ? 2 : 1;
    __shared__ f16 sA[NB][128 * 64];
    __shared__ f16 sB[NB][128 * 64];
    const int tid = threadIdx.x, lane = tid & 63, wid = tid >> 6;
    const int wr = wid >> 1, wc = wid & 1;
    const int bm = blockIdx.x * 128, bn = blockIdx.y * 128;

    f32x4 acc[4][4] = {};

    auto stage16 = [&](int kt, int bsel) {
        const f16* A = (const f16*)Av;
        const f16* B = (const f16*)Bv;
        const int rsub = lane >> 3;
        const int csw = ((lane & 7) ^ rsub) << 3;
#pragma unroll
        for (int i = 0; i < 4; ++i) {
            const int rb = (wid * 4 + i) * 8;
            gload16(A + (size_t)(bm + rb + rsub) * lda + kt + csw, &sA[bsel][rb * 64]);
            gload16(B + (size_t)(bn + rb + rsub) * ldb + kt + csw, &sB[bsel][rb * 64]);
        }
    };

    auto compute = [&](int bsel) {
#pragma unroll
        for (int ks = 0; ks < 2; ++ks) {
            const int kk = ks * 32 + (lane >> 4) * 8;
            f16x8 a[4], b[4];
#pragma unroll
            for (int i = 0; i < 4; ++i) {
                const int ra = wr * 64 + i * 16 + (lane & 15);
                a[i] = *(const f16x8*)(&sA[bsel][(ra << 6) + (kk ^ ((ra & 7) << 3))]);
                const int rb2 = wc * 64 + i * 16 + (lane & 15);
                b[i] = *(const f16x8*)(&sB[bsel][(rb2 << 6) + (kk ^ ((rb2 & 7) << 3))]);
            }
#pragma unroll
            for (int i = 0; i < 4; ++i)
#pragma unroll
                for (int j = 0; j < 4; ++j)
                    acc[i][j] = __builtin_amdgcn_mfma_f32_16x16x32_f16(a[i], b[j], acc[i][j], 0, 0, 0);
        }
    };

    if constexpr (PIPE) {
        stage16(0, 0);
        asm volatile("s_waitcnt vmcnt(0)" ::: "memory");
        __syncthreads();
        const int NT2 = K >> 6;
        for (int t = 0; t < NT2; ++t) {
            if (t + 1 < NT2) stage16((t + 1) << 6, (t + 1) & 1);
            compute(t & 1);
            asm volatile("s_waitcnt vmcnt(0)" ::: "memory");
            __builtin_amdgcn_s_barrier();
        }
    } else {
        for (int kt = 0; kt < K; kt += 64) {
            __syncthreads();
            stage16(kt, 0);
            __syncthreads();
            compute(0);
        }
    }
    if constexpr (PACK) {
#pragma unroll
        for (int i = 0; i < 4; ++i)
#pragma unroll
            for (int r = 0; r < 4; ++r) {
                const int row = bm + wr * 64 + i * 16 + (lane >> 4) * 4 + r;
                f16x4 pk = { (f16)acc[i][0][r], (f16)acc[i][1][r],
                             (f16)acc[i][2][r], (f16)acc[i][3][r] };
                *(f16x4*)((f16*)Cv + (size_t)row * ldc + bn + wc * 64 + (lane & 15) * 4) = pk;
            }
    } else {
#pragma unroll
        for (int i = 0; i < 4; ++i)
#pragma unroll
            for (int j = 0; j < 4; ++j)
#pragma unroll
                for (int r = 0; r < 4; ++r) {
                    const int row = bm + wr * 64 + i * 16 + (lane >> 4) * 4 + r;
                    const int col = bn + wc * 64 + j * 16 + (lane & 15);
                    if constexpr (F16OUT)
                        ((f16*)Cv)[(size_t)row * ldc + col] = (f16)acc[i][j][r];
                    else
                        ((float*)Cv)[(size_t)row * ldc + col] = acc[i][j][r] * scale;
                }
    }
}

// ---------------------------------------------------------------------------
__global__ __launch_bounds__(256) void cvt_f16(
    const float* __restrict__ s, f16* __restrict__ d, int n8)
{
    int i = blockIdx.x * 256 + threadIdx.x;
    const int stride = gridDim.x * 256;
    for (; i < n8; i += stride) {
        const float4 a = ((const float4*)s)[i * 2];
        const float4 b = ((const float4*)s)[i * 2 + 1];
        f16x8 o = { (f16)a.x, (f16)a.y, (f16)a.z, (f16)a.w,
                    (f16)b.x, (f16)b.y, (f16)b.z, (f16)b.w };
        ((f16x8*)d)[i] = o;
    }
}

// ---------------------------------------------------------------------------
// Pipeline: cvt -> proj(bt8) -> per batch { QK+tile-softmax(pi-packed P) ->
// scale_p -> cvt x_b,Wv -> vT(PIPE, pi-packed) -> PV(split-K=4, pi-packed
// partials) -> reduce }.
// ws: P f16 [4096][4096] @0; stats 512KB / partials 24MB @32MB (disjoint
// lifetimes: stats die after scale_p, partials live only in PV+reduce);
// vT [1024][4096] @56MB.
// ---------------------------------------------------------------------------
extern "C" void kernel_launch(void* const* d_in, const int* in_sizes, int n_in,
                              void* d_out, int out_size, void* d_ws, size_t ws_size,
                              hipStream_t stream) {
    const float* x  = (const float*)d_in[0];   // [4,4096,1024]
    const float* Wq = (const float*)d_in[1];   // [1024,1024]
    const float* Wk = (const float*)d_in[2];
    const float* Wv = (const float*)d_in[3];
    float* out = (float*)d_out;                // [4,4096,1024] fp32

    f16*   qk  = (f16*)d_out;                  // q even 1KB-slots, k odd
    f16*   xh  = (f16*)d_ws;                   // 32 MB (transient, pre-proj)
    f16*   wqh = xh + 16384LL * 1024;          // 2 MB (transient)
    f16*   wkh = wqh + 1024LL * 1024;          // 2 MB (transient)

    f16*   P   = (f16*)d_ws;                                   // 32 MB
    float* mst = (float*)((char*)d_ws + (32LL << 20));         // 256 KB
    float* sst = mst + 16 * 4096;                              // 256 KB
    f16*   Pp  = (f16*)((char*)d_ws + (32LL << 20));           // partials 24 MB
    f16*   vTw = (f16*)((char*)d_ws + (56LL << 20));           // 8 MB

    cvt_f16<<<1024, 256, 0, stream>>>(x,  xh,  16384 * 1024 / 8);
    cvt_f16<<<512,  256, 0, stream>>>(Wq, wqh, 1024 * 1024 / 8);
    cvt_f16<<<512,  256, 0, stream>>>(Wk, wkh, 1024 * 1024 / 8);

    gemm_bt8<true><<<256, 512, 0, stream>>>(xh, wqh, qk,        1024, 1024, 1024, 2048, 1.f, 4);
    gemm_bt8<true><<<256, 512, 0, stream>>>(xh, wkh, qk + 1024, 1024, 1024, 1024, 2048, 1.f, 4);

    for (int b = 0; b < 4; ++b) {
        const size_t tb = (size_t)b * 4096;
        f16* xhb = (f16*)(out + tb * 1024);        // dead q_b/k_b region
        f16* wvh = xhb + 4096LL * 1024;            // +8 MB
        // P_t = exp(q_b k_b^T - m_t) (pi-packed), stats m_t,s_t
        gemm_qk<<<256, 512, 0, stream>>>(
            qk + tb * 2048, qk + tb * 2048 + 1024, P, mst, sst, 2048, 2048);
        // fold global softmax correction + 1/32 into P
        scale_p<<<4096, 256, 0, stream>>>(P, mst, sst);
        // re-cvt x_b, Wv into dead out_b region
        cvt_f16<<<1024, 256, 0, stream>>>(x + tb * 1024, xhb, 4096 * 1024 / 8);
        cvt_f16<<<512,  256, 0, stream>>>(Wv, wvh, 1024 * 1024 / 8);
        // vT_b = Wv_h x_b^T -> ws[56:64), compact ldc 4096, pi-packed cols
        gemm_bt<true, true, true, true><<<dim3(8, 32), 256, 0, stream>>>(
            wvh, xhb, vTw, 1024, 1024, 1024, 4096, 1.f);
        // att_b = P vT^T: split-K=4, pi-packed partials, then reduce
        gemm_pv8<<<dim3(64, 4), 512, 0, stream>>>(
            P, vTw, out + tb * 1024, Pp, 4096, 4096);
        reduce_pv<<<2048, 256, 0, stream>>>(out + tb * 1024, Pp);
    }
}

// Round 15
// 565.534 us; speedup vs baseline: 1.2643x; 1.2643x over previous
//
#include <hip/hip_runtime.h>
#include <hip/hip_bf16.h>

typedef _Float16 f16;
typedef _Float16 f16x4 __attribute__((ext_vector_type(4)));
typedef _Float16 f16x8 __attribute__((ext_vector_type(8)));
typedef float f32x4 __attribute__((ext_vector_type(4)));

__device__ __forceinline__ void gload16(const void* g, void* l) {
    __builtin_amdgcn_global_load_lds(
        (const __attribute__((address_space(1))) void*)g,
        (__attribute__((address_space(3))) void*)l, 16, 0, 0);
}

#define FENCE asm volatile("" ::: "memory")
#define BARRIER do { FENCE; __builtin_amdgcn_s_barrier(); FENCE; } while (0)

// ===========================================================================
// 8-phase 256x256 BT-GEMM core (verified r8-r12).
// ===========================================================================
#define PHASE_MFMA(QI, QJ)                                                    \
    __builtin_amdgcn_s_setprio(1);                                            \
    _Pragma("unroll")                                                         \
    for (int ks = 0; ks < 2; ++ks)                                            \
      _Pragma("unroll")                                                       \
      for (int i = 0; i < 4; ++i)                                             \
        _Pragma("unroll")                                                     \
        for (int j = 0; j < 2; ++j)                                           \
          acc[(QI)*4 + i][(QJ)*2 + j] = __builtin_amdgcn_mfma_f32_16x16x32_f16( \
              a[i][ks], b[j][ks], acc[(QI)*4 + i][(QJ)*2 + j], 0, 0, 0);      \
    __builtin_amdgcn_s_setprio(0);

#define BT8_BODY(KBASE, NTILES)                                               \
    const int rr8 = lane >> 3;                                                \
    const int cs  = ((lane & 7) ^ rr8) << 3;                                  \
    const int ldsr = wid << 3;                                                \
    auto stageA = [&](int kt, int c, int h) {                                 \
        const size_t g0 = (size_t)(bm + (h << 7) + ldsr + rr8) * lda + (KBASE) + kt + cs; \
        gload16(A + g0,                      &sA[c][((h << 7) + ldsr) << 6]); \
        gload16(A + g0 + ((size_t)lda << 6), &sA[c][((h << 7) + 64 + ldsr) << 6]); \
    };                                                                        \
    auto stageB = [&](int kt, int c, int h) {                                 \
        const size_t g0 = (size_t)(bn + (h << 7) + ldsr + rr8) * ldb + (KBASE) + kt + cs; \
        gload16(B + g0,                      &sB[c][((h << 7) + ldsr) << 6]); \
        gload16(B + g0 + ((size_t)ldb << 6), &sB[c][((h << 7) + 64 + ldsr) << 6]); \
    };                                                                        \
    f32x4 acc[8][4] = {};                                                     \
    f16x8 a[4][2], b[2][2];                                                   \
    auto loadA = [&](int c, int qi) {                                         \
        _Pragma("unroll")                                                     \
        for (int i = 0; i < 4; ++i) {                                         \
            const int ra = wr * 128 + (qi * 4 + i) * 16 + (lane & 15);        \
            const int swz = (ra & 7) << 3;                                    \
            _Pragma("unroll")                                                 \
            for (int ks = 0; ks < 2; ++ks) {                                  \
                const int kk = ks * 32 + (lane >> 4) * 8;                     \
                a[i][ks] = *(const f16x8*)(&sA[c][(ra << 6) + (kk ^ swz)]);   \
            }                                                                 \
        }                                                                     \
    };                                                                        \
    auto loadB = [&](int c, int qj) {                                         \
        _Pragma("unroll")                                                     \
        for (int j = 0; j < 2; ++j) {                                         \
            const int rb = wc * 64 + (qj * 2 + j) * 16 + (lane & 15);         \
            const int swz = (rb & 7) << 3;                                    \
            _Pragma("unroll")                                                 \
            for (int ks = 0; ks < 2; ++ks) {                                  \
                const int kk = ks * 32 + (lane >> 4) * 8;                     \
                b[j][ks] = *(const f16x8*)(&sB[c][(rb << 6) + (kk ^ swz)]);   \
            }                                                                 \
        }                                                                     \
    };                                                                        \
    stageA(0, 0, 0); stageA(0, 0, 1); stageB(0, 0, 0); stageB(0, 0, 1);       \
    asm volatile("s_waitcnt vmcnt(0)" ::: "memory");                          \
    BARRIER;                                                                  \
    for (int g = 0; g < (NTILES); ++g) {                                      \
        const int c = g & 1, cn = c ^ 1;                                      \
        const int kn = (g + 1) << 6;                                          \
        const bool more = (g + 1) < (NTILES);                                 \
        loadA(c, 0); loadB(c, 0);                                             \
        if (more) { stageA(kn, cn, 0); stageA(kn, cn, 1); }                   \
        BARRIER; PHASE_MFMA(0, 0); BARRIER;                                   \
        loadB(c, 1);                                                          \
        if (more) { stageB(kn, cn, 0); stageB(kn, cn, 1); }                   \
        BARRIER; PHASE_MFMA(0, 1); BARRIER;                                   \
        loadA(c, 1); loadB(c, 0);                                             \
        BARRIER; PHASE_MFMA(1, 0); BARRIER;                                   \
        loadB(c, 1);                                                          \
        asm volatile("s_waitcnt vmcnt(0)" ::: "memory");                      \
        BARRIER; PHASE_MFMA(1, 1); BARRIER;                                   \
    }

// ===========================================================================
// Projection GEMM (verified): C = A B^T, f16 in, f16 out, ldc-interleaved.
// ===========================================================================
template<bool F16OUT>
__global__ __launch_bounds__(512) void gemm_bt8(
    const f16* __restrict__ A, const f16* __restrict__ B, void* __restrict__ Cv,
    int K, int lda, int ldb, int ldc, float scale, int nbn)
{
    __shared__ f16 sA[2][256 * 64];
    __shared__ f16 sB[2][256 * 64];
    const int tid = threadIdx.x, lane = tid & 63, wid = tid >> 6;
    const int wr = wid >> 2, wc = wid & 3;
    const int cpx = gridDim.x >> 3;
    const int wg = (blockIdx.x & 7) * cpx + (blockIdx.x >> 3);
    const int bm = (wg / nbn) << 8, bn = (wg % nbn) << 8;

    BT8_BODY(0, K >> 6)

#pragma unroll
    for (int i = 0; i < 8; ++i)
#pragma unroll
        for (int j = 0; j < 4; ++j)
#pragma unroll
            for (int r = 0; r < 4; ++r) {
                const int row = bm + wr * 128 + i * 16 + ((lane >> 4) << 2) + r;
                const int col = bn + wc * 64 + j * 16 + (lane & 15);
                if constexpr (F16OUT)
                    ((f16*)Cv)[(size_t)row * ldc + col] = (f16)(acc[i][j][r] * scale);
                else
                    ((float*)Cv)[(size_t)row * ldc + col] = acc[i][j][r] * scale;
            }
}

// ===========================================================================
// QK: bt8 core, S written as PLAIN f16 via LDS-transpose epilogue ->
// fully packed 16B stores. No softmax here (kept minimal vs r12).
// LDS swizzle key ((rloc>>2)&7)<<3 -> 2-way max on write, free on read.
// ===========================================================================
__global__ __launch_bounds__(512) void gemm_qk(
    const f16* __restrict__ A, const f16* __restrict__ B,
    f16* __restrict__ S, int lda, int ldb)
{
    __shared__ f16 sA[2][256 * 64];
    __shared__ f16 sB[2][256 * 64];
    const int tid = threadIdx.x, lane = tid & 63, wid = tid >> 6;
    const int wr = wid >> 2, wc = wid & 3;
    const int cpx = gridDim.x >> 3;
    const int wg = (blockIdx.x & 7) * cpx + (blockIdx.x >> 3);
    const int bm = (wg >> 4) << 8, bn = (wg & 15) << 8;   // nbn = 16

    BT8_BODY(0, 16)

    // ---- acc -> LDS f16 (sA/sB dead; wr=0 half -> sA, wr=1 half -> sB) ----
    {
        f16* Tb = wr ? (f16*)sB : (f16*)sA;
        const int lg = lane >> 4;
#pragma unroll
        for (int i = 0; i < 8; ++i)
#pragma unroll
            for (int j = 0; j < 4; ++j)
#pragma unroll
                for (int r = 0; r < 4; ++r) {
                    const int rloc = i * 16 + lg * 4 + r;          // 0..127
                    const int col  = wc * 64 + j * 16 + (lane & 15);
                    Tb[rloc * 256 + (col ^ (((rloc >> 2) & 7) << 3))] = (f16)acc[i][j][r];
                }
    }
    BARRIER;
    // ---- LDS -> global: f16x8 per thread-iter, 512B contiguous per row ----
#pragma unroll
    for (int u = 0; u < 16; ++u) {
        const int gi = u * 512 + tid;
        const int row = gi >> 5;                 // 0..255
        const int c0 = (gi & 31) << 3;
        const f16* Tb = (row & 128) ? (const f16*)sB : (const f16*)sA;
        f16x8 v = *(const f16x8*)(Tb + (row & 127) * 256
                                  + (c0 ^ (((row >> 2) & 7) << 3)));
        *(f16x8*)(S + (size_t)(bm + row) * 4096 + bn + c0) = v;
    }
}

// ===========================================================================
// In-place row softmax on f16 S: P = exp(S - m) / (32 l), same location.
// One wave per 4096-half row; packed f16x8 loads/stores.
// ===========================================================================
__global__ __launch_bounds__(256) void softmax_f16(f16* S)
{
    const int lane = threadIdx.x & 63, wid = threadIdx.x >> 6;
    const int row = blockIdx.x * 4 + wid;
    f16* src = S + (size_t)row * 4096;
    f16x8 v[8];
#pragma unroll
    for (int u = 0; u < 8; ++u) v[u] = *(const f16x8*)(src + u * 512 + lane * 8);
    float m = -1e30f;
#pragma unroll
    for (int u = 0; u < 8; ++u)
#pragma unroll
        for (int e = 0; e < 8; ++e) m = fmaxf(m, (float)v[u][e]);
#pragma unroll
    for (int msk = 1; msk <= 32; msk <<= 1) m = fmaxf(m, __shfl_xor(m, msk));
    float ev[64];
    float s = 0.f;
#pragma unroll
    for (int u = 0; u < 8; ++u)
#pragma unroll
        for (int e = 0; e < 8; ++e) {
            const float x = __expf((float)v[u][e] - m);
            ev[u * 8 + e] = x; s += x;
        }
#pragma unroll
    for (int msk = 1; msk <= 32; msk <<= 1) s += __shfl_xor(s, msk);
    const float inv = 1.0f / (32.0f * s);
#pragma unroll
    for (int u = 0; u < 8; ++u) {
        f16x8 p;
#pragma unroll
        for (int e = 0; e < 8; ++e) p[e] = (f16)(ev[u * 8 + e] * inv);
        *(f16x8*)(src + u * 512 + lane * 8) = p;
    }
}

// ===========================================================================
// PV: bt8 core + split-K=4, plain stores (r13-verified flat layout).
// z=3 -> f32 direct to out; z=0..2 -> f16 partials [z][4096][1024].
// ===========================================================================
__global__ __launch_bounds__(512) void gemm_pv8(
    const f16* __restrict__ A, const f16* __restrict__ B, float* __restrict__ Cout,
    f16* __restrict__ Pp, int lda, int ldb)
{
    __shared__ f16 sA[2][256 * 64];
    __shared__ f16 sB[2][256 * 64];
    const int tid = threadIdx.x, lane = tid & 63, wid = tid >> 6;
    const int wr = wid >> 2, wc = wid & 3;
    const int cpx = gridDim.x >> 3;
    const int wg = (blockIdx.x & 7) * cpx + (blockIdx.x >> 3);
    const int bm = (wg >> 2) << 8, bn = (wg & 3) << 8;
    const int z = blockIdx.y;
    const int kbase = z << 10;

    BT8_BODY(kbase, 16)

#pragma unroll
    for (int i = 0; i < 8; ++i)
#pragma unroll
        for (int j = 0; j < 4; ++j)
#pragma unroll
            for (int r = 0; r < 4; ++r) {
                const int row = bm + wr * 128 + i * 16 + ((lane >> 4) << 2) + r;
                const int col = bn + wc * 64 + j * 16 + (lane & 15);
                const float v = acc[i][j][r];
                if (z == 3)
                    Cout[((size_t)row << 10) + col] = v;
                else
                    Pp[(size_t)z * 4194304 + ((size_t)row << 10) + col] = (f16)v;
            }
}

// ===========================================================================
// reduce_pv: out[r][c] = out[r][c](=p3) + p0 + p1 + p2 (flat partials).
// ===========================================================================
__global__ __launch_bounds__(256) void reduce_pv(
    float* __restrict__ Cout, const f16* __restrict__ Pp)
{
    const int i = blockIdx.x * 256 + threadIdx.x;
    const int r = i >> 7;
    const int c = (i & 127) << 3;
    const size_t base = ((size_t)r << 10) + c;
    const f16x8 p0 = *(const f16x8*)(Pp + base);
    const f16x8 p1 = *(const f16x8*)(Pp + base + 4194304);
    const f16x8 p2 = *(const f16x8*)(Pp + base + 8388608);
    float* o = Cout + base;
    float4 o0 = *(float4*)o, o1 = *(float4*)(o + 4);
    o0.x += (float)p0[0] + (float)p1[0] + (float)p2[0];
    o0.y += (float)p0[1] + (float)p1[1] + (float)p2[1];
    o0.z += (float)p0[2] + (float)p1[2] + (float)p2[2];
    o0.w += (float)p0[3] + (float)p1[3] + (float)p2[3];
    o1.x += (float)p0[4] + (float)p1[4] + (float)p2[4];
    o1.y += (float)p0[5] + (float)p1[5] + (float)p2[5];
    o1.z += (float)p0[6] + (float)p1[6] + (float)p2[6];
    o1.w += (float)p0[7] + (float)p1[7] + (float)p2[7];
    *(float4*)o = o0;
    *(float4*)(o + 4) = o1;
}

// ===========================================================================
// 128x128 BT-GEMM, F16IN + PIPE (verified) — used for vT.
// ===========================================================================
__global__ __launch_bounds__(256) void gemm_vt(
    const f16* __restrict__ A, const f16* __restrict__ B, f16* __restrict__ C,
    int K, int lda, int ldb, int ldc)
{
    __shared__ f16 sA[2][128 * 64];
    __shared__ f16 sB[2][128 * 64];
    const int tid = threadIdx.x, lane = tid & 63, wid = tid >> 6;
    const int wr = wid >> 1, wc = wid & 1;
    const int bm = blockIdx.x * 128, bn = blockIdx.y * 128;

    f32x4 acc[4][4] = {};

    auto stage16 = [&](int kt, int bsel) {
        const int rsub = lane >> 3;
        const int csw = ((lane & 7) ^ rsub) << 3;
#pragma unroll
        for (int i = 0; i < 4; ++i) {
            const int rb = (wid * 4 + i) * 8;
            gload16(A + (size_t)(bm + rb + rsub) * lda + kt + csw, &sA[bsel][rb * 64]);
            gload16(B + (size_t)(bn + rb + rsub) * ldb + kt + csw, &sB[bsel][rb * 64]);
        }
    };

    auto compute = [&](int bsel) {
#pragma unroll
        for (int ks = 0; ks < 2; ++ks) {
            const int kk = ks * 32 + (lane >> 4) * 8;
            f16x8 a[4], b[4];
#pragma unroll
            for (int i = 0; i < 4; ++i) {
                const int ra = wr * 64 + i * 16 + (lane & 15);
                a[i] = *(const f16x8*)(&sA[bsel][(ra << 6) + (kk ^ ((ra & 7) << 3))]);
                const int rb2 = wc * 64 + i * 16 + (lane & 15);
                b[i] = *(const f16x8*)(&sB[bsel][(rb2 << 6) + (kk ^ ((rb2 & 7) << 3))]);
            }
#pragma unroll
            for (int i = 0; i < 4; ++i)
#pragma unroll
                for (int j = 0; j < 4; ++j)
                    acc[i][j] = __builtin_amdgcn_mfma_f32_16x16x32_f16(a[i], b[j], acc[i][j], 0, 0, 0);
        }
    };

    stage16(0, 0);
    asm volatile("s_waitcnt vmcnt(0)" ::: "memory");
    __syncthreads();
    const int NT2 = K >> 6;
    for (int t = 0; t < NT2; ++t) {
        if (t + 1 < NT2) stage16((t + 1) << 6, (t + 1) & 1);
        compute(t & 1);
        asm volatile("s_waitcnt vmcnt(0)" ::: "memory");
        __builtin_amdgcn_s_barrier();
    }
#pragma unroll
    for (int i = 0; i < 4; ++i)
#pragma unroll
        for (int j = 0; j < 4; ++j)
#pragma unroll
            for (int r = 0; r < 4; ++r) {
                const int row = bm + wr * 64 + i * 16 + (lane >> 4) * 4 + r;
                const int col = bn + wc * 64 + j * 16 + (lane & 15);
                C[(size_t)row * ldc + col] = (f16)acc[i][j][r];
            }
}

// ---------------------------------------------------------------------------
// Merged upfront convert: x (2097152 x8), Wq (131072 x8), Wk (131072 x8).
// ---------------------------------------------------------------------------
__global__ __launch_bounds__(256) void cvt3(
    const float* __restrict__ x, const float* __restrict__ wq, const float* __restrict__ wk,
    f16* __restrict__ dx, f16* __restrict__ dwq, f16* __restrict__ dwk)
{
    const int i = blockIdx.x * 256 + threadIdx.x;
    const float* s; f16* d; int off;
    if (i < 2097152)      { s = x;  d = dx;  off = i; }
    else if (i < 2228224) { s = wq; d = dwq; off = i - 2097152; }
    else                  { s = wk; d = dwk; off = i - 2228224; }
    const float4 a = ((const float4*)s)[off * 2];
    const float4 b = ((const float4*)s)[off * 2 + 1];
    f16x8 o = { (f16)a.x, (f16)a.y, (f16)a.z, (f16)a.w,
                (f16)b.x, (f16)b.y, (f16)b.z, (f16)b.w };
    ((f16x8*)d)[off] = o;
}

// Merged per-batch convert: x_b (524288 x8) + Wv (131072 x8).
__global__ __launch_bounds__(256) void cvt_batch(
    const float* __restrict__ xb, const float* __restrict__ wv,
    f16* __restrict__ dxb, f16* __restrict__ dwv)
{
    const int i = blockIdx.x * 256 + threadIdx.x;
    const float* s; f16* d; int off;
    if (i < 524288) { s = xb; d = dxb; off = i; }
    else            { s = wv; d = dwv; off = i - 524288; }
    const float4 a = ((const float4*)s)[off * 2];
    const float4 b = ((const float4*)s)[off * 2 + 1];
    f16x8 o = { (f16)a.x, (f16)a.y, (f16)a.z, (f16)a.w,
                (f16)b.x, (f16)b.y, (f16)b.z, (f16)b.w };
    ((f16x8*)d)[off] = o;
}

// ---------------------------------------------------------------------------
// Pipeline: cvt3 -> proj(bt8 x2) -> per batch { QK(f16 S, LDS-transpose) ->
// softmax_f16(in place) -> cvt_batch -> vT(PIPE) -> PV(split-K=4) -> reduce }.
// ws: S/P f16 [4096][4096] @0 (32MB); partials [3][4096][1024] @32MB (24MB);
// vT [1024][4096] @56MB (8MB). Pre-loop: xh@0, wqh/wkh@32MB (dead after proj).
// ---------------------------------------------------------------------------
extern "C" void kernel_launch(void* const* d_in, const int* in_sizes, int n_in,
                              void* d_out, int out_size, void* d_ws, size_t ws_size,
                              hipStream_t stream) {
    const float* x  = (const float*)d_in[0];   // [4,4096,1024]
    const float* Wq = (const float*)d_in[1];   // [1024,1024]
    const float* Wk = (const float*)d_in[2];
    const float* Wv = (const float*)d_in[3];
    float* out = (float*)d_out;                // [4,4096,1024] fp32

    f16*   qk  = (f16*)d_out;                  // q even 1KB-slots, k odd
    f16*   xh  = (f16*)d_ws;                   // 32 MB (transient)
    f16*   wqh = (f16*)((char*)d_ws + (32LL << 20));   // 2 MB (transient)
    f16*   wkh = wqh + 1024LL * 1024;                  // 2 MB (transient)

    f16*   S   = (f16*)d_ws;                                  // 32 MB S/P
    f16*   Pp  = (f16*)((char*)d_ws + (32LL << 20));          // 24 MB partials
    f16*   vTw = (f16*)((char*)d_ws + (56LL << 20));          // 8 MB vT

    cvt3<<<9216, 256, 0, stream>>>(x, Wq, Wk, xh, wqh, wkh);

    gemm_bt8<true><<<256, 512, 0, stream>>>(xh, wqh, qk,        1024, 1024, 1024, 2048, 1.f, 4);
    gemm_bt8<true><<<256, 512, 0, stream>>>(xh, wkh, qk + 1024, 1024, 1024, 1024, 2048, 1.f, 4);

    for (int b = 0; b < 4; ++b) {
        const size_t tb = (size_t)b * 4096;
        f16* xhb = (f16*)(out + tb * 1024);        // dead q_b/k_b region
        f16* wvh = xhb + 4096LL * 1024;            // +8 MB
        // S = q_b k_b^T  (f16, packed stores via LDS transpose)
        gemm_qk<<<256, 512, 0, stream>>>(
            qk + tb * 2048, qk + tb * 2048 + 1024, S, 2048, 2048);
        // P = exp(S - m) / (32 l), in place
        softmax_f16<<<1024, 256, 0, stream>>>(S);
        // cvt x_b + Wv into dead out_b region (one launch)
        cvt_batch<<<2560, 256, 0, stream>>>(x + tb * 1024, Wv, xhb, wvh);
        // vT_b = Wv_h x_b^T -> ws[56:64), ldc 4096
        gemm_vt<<<dim3(8, 32), 256, 0, stream>>>(wvh, xhb, vTw, 1024, 1024, 1024, 4096);
        // att_b = P vT^T: split-K=4, then reduce
        gemm_pv8<<<dim3(64, 4), 512, 0, stream>>>(S, vTw, out + tb * 1024, Pp, 4096, 4096);
        reduce_pv<<<2048, 256, 0, stream>>>(out + tb * 1024, Pp);
    }
}